// Round 7
// baseline (471.048 us; speedup 1.0000x reference)
//
#include <hip/hip_runtime.h>

// 2-layer LSTM, B=1024 T=512 D=1 H=64.
// R7: 512 blocks x 256 threads, MB=2 batches/block -> 2 blocks/CU co-resident
// (block-level overlap fills each block's serial stalls: ds_read latency,
// barrier waits, MFMA latency). Waves 0-1 = layer0 (unit halves), waves 2-3 =
// layer1. MFMA M=2 (rows 2-15 zero/ignored). Pointwise: 1 point/lane after
// 4-shfl gate select. One __syncthreads per step, parity double-buffers.

typedef _Float16 f16x8 __attribute__((ext_vector_type(8)));
typedef float f32x4 __attribute__((ext_vector_type(4)));

#define TSTEPS 512
#define MB 2
#define L2E 1.44269504088896340736f

__device__ __forceinline__ int hidx(int row, int j) {
    // swizzled index into a 16x64 half tile
    return row * 64 + ((((j >> 3) ^ (row & 7)) << 3) | (j & 7));
}

__device__ __forceinline__ float lstm_point(float ai, float af, float ag, float ao,
                                            float& c) {
    // ai,af,ao pre-scaled by -log2e ; ag by +2log2e   (R2-R6 proven numerics)
    const float p  = __builtin_amdgcn_exp2f(ai);
    const float s_ = __builtin_amdgcn_exp2f(af);
    const float r_ = __builtin_amdgcn_exp2f(ag);
    const float v  = __builtin_amdgcn_exp2f(ao);
    const float f  = __builtin_amdgcn_rcpf(1.f + s_);
    const float ig = (r_ - 1.f) * __builtin_amdgcn_rcpf((1.f + p) * (1.f + r_));
    const float cc = __builtin_fmaf(f, c, ig);
    c = cc;
    const float w  = __builtin_amdgcn_exp2f(cc * (2.f * L2E));
    return (w - 1.f) * __builtin_amdgcn_rcpf((1.f + v) * (1.f + w));
}

__global__ __launch_bounds__(256, 2) void lstm2_kernel(
    const float* __restrict__ x,
    const float* __restrict__ W_ih0, const float* __restrict__ W_hh0,
    const float* __restrict__ b_ih0, const float* __restrict__ b_hh0,
    const float* __restrict__ W_ih1, const float* __restrict__ W_hh1,
    const float* __restrict__ b_ih1, const float* __restrict__ b_hh1,
    const float* __restrict__ W_fc,  const float* __restrict__ b_fc,
    float* __restrict__ out)
{
    __shared__ __align__(16) _Float16 h0s[2][16 * 64];
    __shared__ __align__(16) _Float16 h1s[2][16 * 64];
    __shared__ __align__(16) float    xlds[64 * MB];   // [step-in-chunk][batch]

    const int tid  = (int)threadIdx.x;
    const int lane = tid & 63;
    const int w    = tid >> 6;          // wave 0..3
    const bool gB  = (w >= 2);          // waves 2-3 = layer1
    const int wl   = w & 1;             // unit-half within layer
    const int c    = lane & 15;
    const int quad = lane >> 4;
    const int b0   = (int)blockIdx.x * MB;

    // this lane's point: batch pb, unit pj  (quad encodes b and u)
    const int pb = quad & 1;                         // batch 0..1
    const int pu = quad >> 1;                        // u 0..1
    const int pj = 16 * (2 * wl + pu) + c;           // unit 0..63
    const int wrH  = hidx(pb, pj);
    const int rdA0 = hidx(c, quad * 8);              // A-frag k 0..31
    const int rdA1 = hidx(c, quad * 8 + 32);         // A-frag k 32..63

    // ---- per-wave register weight fragments ----
    // tile n = 4g + T, T = 2*wl + u ; gate-row = 16n + c
    float biasc[4][2], wih0c[4][2];
    f16x8 bf[4][2][4];   // [gate][u][kchunk]; L0 uses kchunk 0..1, L1 0..3

    if (!gB) {
#pragma unroll
        for (int g = 0; g < 4; ++g) {
            const float sg = (g == 2) ? (2.0f * L2E) : (-L2E);
#pragma unroll
            for (int u = 0; u < 2; ++u) {
                const int row = 64 * g + 16 * (2 * wl + u) + c;
                biasc[g][u] = sg * (b_ih0[row] + b_hh0[row]);
                wih0c[g][u] = sg * W_ih0[row];            // D == 1
#pragma unroll
                for (int kb = 0; kb < 2; ++kb) {
                    const float* p = W_hh0 + row * 64 + kb * 32 + quad * 8;
#pragma unroll
                    for (int q = 0; q < 8; ++q) bf[g][u][kb][q] = (_Float16)(p[q] * sg);
                }
            }
        }
    } else {
#pragma unroll
        for (int g = 0; g < 4; ++g) {
            const float sg = (g == 2) ? (2.0f * L2E) : (-L2E);
#pragma unroll
            for (int u = 0; u < 2; ++u) {
                const int row = 64 * g + 16 * (2 * wl + u) + c;
                biasc[g][u] = sg * (b_ih1[row] + b_hh1[row]);
#pragma unroll
                for (int kb = 0; kb < 4; ++kb) {
                    const int kk = kb * 32 + quad * 8;
                    const float* p = (kk < 64) ? (W_ih1 + row * 64 + kk)
                                               : (W_hh1 + row * 64 + (kk - 64));
#pragma unroll
                    for (int q = 0; q < 8; ++q) bf[g][u][kb][q] = (_Float16)(p[q] * sg);
                }
            }
        }
    }

    // zero-init h buffers (rows 2-15 stay zero forever)
    for (int i = tid; i < 16 * 64; i += 256) {
        h0s[0][i] = (_Float16)0.f; h0s[1][i] = (_Float16)0.f;
        h1s[0][i] = (_Float16)0.f; h1s[1][i] = (_Float16)0.f;
    }

    float cst = 0.f;            // cell state for (pb, pj)
    const f32x4 zf4 = {0.f, 0.f, 0.f, 0.f};

    // gate select: lane(c,quad) <- reg[pb] of acc[g][pu] pulled from lane c
    auto gsel = [&](const f32x4 a0, const f32x4 a1) -> float {
        const float t00 = __shfl(a0[0], c, 64);
        const float t01 = __shfl(a0[1], c, 64);
        const float t10 = __shfl(a1[0], c, 64);
        const float t11 = __shfl(a1[1], c, 64);
        return (quad < 2) ? (quad == 0 ? t00 : t01) : (quad == 2 ? t10 : t11);
    };

    for (int t = 0; t <= TSTEPS; ++t) {
        if (t < TSTEPS && (t & 63) == 0) {
            __syncthreads();                 // prior chunk's xlds reads done
            if (tid < 64 * MB) {
                const int i = tid >> 1, m = tid & 1;
                xlds[i * MB + m] = x[(b0 + m) * TSTEPS + t + i];
            }
            __syncthreads();
        }

        if (!gB) {
            // ===== layer0: h0(t) from h0(t-1), x(t) =====
            if (t < TSTEPS) {
                const int pr = (t + 1) & 1, pw = t & 1;
                const float x0 = xlds[(t & 63) * MB + 0];
                const float x1 = xlds[(t & 63) * MB + 1];
                f32x4 acc[4][2];
#pragma unroll
                for (int g = 0; g < 4; ++g)
#pragma unroll
                    for (int u = 0; u < 2; ++u) {
                        acc[g][u][0] = biasc[g][u] + x0 * wih0c[g][u];
                        acc[g][u][1] = biasc[g][u] + x1 * wih0c[g][u];
                        acc[g][u][2] = acc[g][u][0];
                        acc[g][u][3] = acc[g][u][1];
                    }
                const f16x8 a0 = *(const f16x8*)&h0s[pr][rdA0];
                const f16x8 a1 = *(const f16x8*)&h0s[pr][rdA1];
#pragma unroll
                for (int g = 0; g < 4; ++g)
#pragma unroll
                    for (int u = 0; u < 2; ++u) {
                        acc[g][u] = __builtin_amdgcn_mfma_f32_16x16x32_f16(a0, bf[g][u][0], acc[g][u], 0, 0, 0);
                        acc[g][u] = __builtin_amdgcn_mfma_f32_16x16x32_f16(a1, bf[g][u][1], acc[g][u], 0, 0, 0);
                    }
                const float gi = gsel(acc[0][0], acc[0][1]);
                const float gf = gsel(acc[1][0], acc[1][1]);
                const float gg = gsel(acc[2][0], acc[2][1]);
                const float go = gsel(acc[3][0], acc[3][1]);
                const float hv = lstm_point(gi, gf, gg, go, cst);
                h0s[pw][wrH] = (_Float16)hv;
            }
        } else {
            // ===== layer1: h1(s), s=t-1, from h0(s), h1(s-1) =====
            if (t > 0) {
                const int s = t - 1;
                const int prh0 = s & 1;
                const int prh1 = (s + 1) & 1;
                const int pwh1 = s & 1;
                const f16x8 a10 = *(const f16x8*)&h0s[prh0][rdA0];
                const f16x8 a11 = *(const f16x8*)&h0s[prh0][rdA1];
                const f16x8 a12 = *(const f16x8*)&h1s[prh1][rdA0];
                const f16x8 a13 = *(const f16x8*)&h1s[prh1][rdA1];
                f32x4 accP[4][2], accQ[4][2];
#pragma unroll
                for (int g = 0; g < 4; ++g)
#pragma unroll
                    for (int u = 0; u < 2; ++u) {
                        f32x4 cb;
#pragma unroll
                        for (int r = 0; r < 4; ++r) cb[r] = biasc[g][u];
                        accP[g][u] = __builtin_amdgcn_mfma_f32_16x16x32_f16(a10, bf[g][u][0], cb,  0, 0, 0);
                        accP[g][u] = __builtin_amdgcn_mfma_f32_16x16x32_f16(a11, bf[g][u][1], accP[g][u], 0, 0, 0);
                        accQ[g][u] = __builtin_amdgcn_mfma_f32_16x16x32_f16(a12, bf[g][u][2], zf4, 0, 0, 0);
                        accQ[g][u] = __builtin_amdgcn_mfma_f32_16x16x32_f16(a13, bf[g][u][3], accQ[g][u], 0, 0, 0);
                    }
                const float gi = gsel(accP[0][0] + accQ[0][0], accP[0][1] + accQ[0][1]);
                const float gf = gsel(accP[1][0] + accQ[1][0], accP[1][1] + accQ[1][1]);
                const float gg = gsel(accP[2][0] + accQ[2][0], accP[2][1] + accQ[2][1]);
                const float go = gsel(accP[3][0] + accQ[3][0], accP[3][1] + accQ[3][1]);
                const float hv = lstm_point(gi, gf, gg, go, cst);
                h1s[pwh1][wrH] = (_Float16)hv;
            }
        }
        __syncthreads();
    }

    // ---- epilogue: h0(511), h1(511) both in parity 1 ----
    if (tid < 2 * MB) {
        const int which = tid >> 1, m = tid & 1;
        const _Float16* hb = which ? &h1s[1][0] : &h0s[1][0];
        float s = b_fc[0];
        for (int jj = 0; jj < 64; ++jj) s += (float)hb[hidx(m, jj)] * W_fc[jj];
        out[which * 1024 + b0 + m] = s;
    }
}

extern "C" void kernel_launch(void* const* d_in, const int* in_sizes, int n_in,
                              void* d_out, int out_size, void* d_ws, size_t ws_size,
                              hipStream_t stream) {
    (void)in_sizes; (void)n_in; (void)d_ws; (void)ws_size; (void)out_size;
    lstm2_kernel<<<512, 256, 0, stream>>>(
        (const float*)d_in[0],
        (const float*)d_in[1], (const float*)d_in[2],
        (const float*)d_in[3], (const float*)d_in[4],
        (const float*)d_in[5], (const float*)d_in[6],
        (const float*)d_in[7], (const float*)d_in[8],
        (const float*)d_in[9], (const float*)d_in[10],
        (float*)d_out);
}

// Round 8
// 444.868 us; speedup vs baseline: 1.0589x; 1.0589x over previous
//
#include <hip/hip_runtime.h>

// 2-layer LSTM, B=1024 T=512 D=1 H=64. 64 blocks x 1024 threads (16 waves).
// MB=16 batches/block. Waves 0-7 = layer0 step t; waves 8-15 = layer1 step t-1.
// Operand-swapped MFMA: A = pre-gathered W tiles (16 rows = 4 units x 4 gates,
// row 4u'+g), B = h (k=unit, n=batch). D gives lane (c,quad) all 4 gates of
// (batch=c, unit=4*tile+quad) -> no shuffles, 2 tiles/wave = 2 points/lane.
// One __syncthreads per step; h tiles XOR-swizzled f16, parity double-buffered.

typedef _Float16 f16x8 __attribute__((ext_vector_type(8)));
typedef float f32x4 __attribute__((ext_vector_type(4)));

#define TSTEPS 512
#define MB 16
#define XP 17          // xlds row pad (dwords)
#define L2E 1.44269504088896340736f

__device__ __forceinline__ int hidx(int row, int j) {
    // swizzled index into a 16x64 half tile (16B-block XOR swizzle)
    return row * 64 + ((((j >> 3) ^ (row & 7)) << 3) | (j & 7));
}

__device__ __forceinline__ float lstm_point(float ai, float af, float ag, float ao,
                                            float& c) {
    // ai,af,ao pre-scaled by -log2e ; ag by +2log2e  (R2-R7 proven numerics)
    const float p  = __builtin_amdgcn_exp2f(ai);
    const float s_ = __builtin_amdgcn_exp2f(af);
    const float r_ = __builtin_amdgcn_exp2f(ag);
    const float v  = __builtin_amdgcn_exp2f(ao);
    const float f  = __builtin_amdgcn_rcpf(1.f + s_);
    const float ig = (r_ - 1.f) * __builtin_amdgcn_rcpf((1.f + p) * (1.f + r_));
    const float cc = __builtin_fmaf(f, c, ig);
    c = cc;
    const float w  = __builtin_amdgcn_exp2f(cc * (2.f * L2E));
    return (w - 1.f) * __builtin_amdgcn_rcpf((1.f + v) * (1.f + w));
}

__global__ __launch_bounds__(1024) void lstm2_kernel(
    const float* __restrict__ x,
    const float* __restrict__ W_ih0, const float* __restrict__ W_hh0,
    const float* __restrict__ b_ih0, const float* __restrict__ b_hh0,
    const float* __restrict__ W_ih1, const float* __restrict__ W_hh1,
    const float* __restrict__ b_ih1, const float* __restrict__ b_hh1,
    const float* __restrict__ W_fc,  const float* __restrict__ b_fc,
    float* __restrict__ out)
{
    __shared__ __align__(16) _Float16 h0s[2][16 * 64];
    __shared__ __align__(16) _Float16 h1s[2][16 * 64];
    __shared__ __align__(16) float    xlds[64 * XP];   // [step-in-chunk][batch]

    const int tid  = (int)threadIdx.x;
    const int lane = tid & 63;
    const int w16  = tid >> 6;          // wave 0..15
    const bool gB  = (w16 >= 8);        // waves 8-15 = layer1
    const int wl   = w16 & 7;           // wave within layer, owns tiles {2wl, 2wl+1}
    const int c    = lane & 15;         // batch (D col)
    const int quad = lane >> 4;
    const int b0   = (int)blockIdx.x * MB;

    const int rdB0 = hidx(c, quad * 8);        // B-frag k 0..31 (n = batch c)
    const int rdB1 = hidx(c, quad * 8 + 32);   // B-frag k 32..63

    // A-row this lane holds (per tile τ): unit 4τ + (c>>2), gate c&3
    const int gA = c & 3;
    const int uA = c >> 2;
    const float sgA = (gA == 2) ? (2.f * L2E) : (-L2E);

    // ---- per-wave register weights: 2 tiles ----
    float bias[2][4], wih0[2][4];
    f16x8 aW[2][4];       // [tile][kchunk]; L0 uses 0..1, L1 uses 0..3
    int   wrU[2];         // unit this lane's point covers, per tile

#pragma unroll
    for (int ti = 0; ti < 2; ++ti) {
        const int tau = 2 * wl + ti;
        const int rho = 64 * gA + 4 * tau + uA;    // global W row held as A[m=c]
        wrU[ti] = 4 * tau + quad;
        if (!gB) {
#pragma unroll
            for (int kb = 0; kb < 2; ++kb) {
                const float* p = W_hh0 + rho * 64 + kb * 32 + quad * 8;
#pragma unroll
                for (int q = 0; q < 8; ++q) aW[ti][kb][q] = (_Float16)(p[q] * sgA);
            }
#pragma unroll
            for (int r = 0; r < 4; ++r) {
                const float sg = (r == 2) ? (2.f * L2E) : (-L2E);
                const int row = 64 * r + 4 * tau + quad;   // D row: gate r, unit wrU
                bias[ti][r] = sg * (b_ih0[row] + b_hh0[row]);
                wih0[ti][r] = sg * W_ih0[row];             // D == 1
            }
        } else {
#pragma unroll
            for (int kb = 0; kb < 4; ++kb) {
                const int kk = kb * 32 + quad * 8;
                const float* p = (kk < 64) ? (W_ih1 + rho * 64 + kk)
                                           : (W_hh1 + rho * 64 + kk - 64);
#pragma unroll
                for (int q = 0; q < 8; ++q) aW[ti][kb][q] = (_Float16)(p[q] * sgA);
            }
#pragma unroll
            for (int r = 0; r < 4; ++r) {
                const float sg = (r == 2) ? (2.f * L2E) : (-L2E);
                const int row = 64 * r + 4 * tau + quad;
                bias[ti][r] = sg * (b_ih1[row] + b_hh1[row]);
            }
        }
    }

    // zero-init h buffers
    for (int i = tid; i < 16 * 64; i += 1024) {
        h0s[0][i] = (_Float16)0.f; h0s[1][i] = (_Float16)0.f;
        h1s[0][i] = (_Float16)0.f; h1s[1][i] = (_Float16)0.f;
    }

    float cst[2] = {0.f, 0.f};
    const f32x4 zf4 = {0.f, 0.f, 0.f, 0.f};

    for (int t = 0; t <= TSTEPS; ++t) {
        if (t < TSTEPS && (t & 63) == 0) {
            __syncthreads();                 // prior chunk's xlds reads done
            {   // 64 steps x 16 batches; coalesced over time
                const int m = tid >> 6, i = tid & 63;
                xlds[i * XP + m] = x[(b0 + m) * TSTEPS + t + i];
            }
            __syncthreads();
        }

        if (!gB) {
            // ===== layer0: h0(t) from h0(t-1), x(t) =====
            if (t < TSTEPS) {
                const int pr = (t + 1) & 1, pw = t & 1;
                const float xv = xlds[(t & 63) * XP + c];   // x[batch c](t)
                const f16x8 bh0 = *(const f16x8*)&h0s[pr][rdB0];
                const f16x8 bh1 = *(const f16x8*)&h0s[pr][rdB1];
                f32x4 acc[2];
#pragma unroll
                for (int ti = 0; ti < 2; ++ti) {
                    f32x4 ci;
#pragma unroll
                    for (int r = 0; r < 4; ++r)
                        ci[r] = __builtin_fmaf(xv, wih0[ti][r], bias[ti][r]);
                    acc[ti] = __builtin_amdgcn_mfma_f32_16x16x32_f16(aW[ti][0], bh0, ci, 0, 0, 0);
                    acc[ti] = __builtin_amdgcn_mfma_f32_16x16x32_f16(aW[ti][1], bh1, acc[ti], 0, 0, 0);
                }
#pragma unroll
                for (int ti = 0; ti < 2; ++ti) {
                    const float hv = lstm_point(acc[ti][0], acc[ti][1],
                                                acc[ti][2], acc[ti][3], cst[ti]);
                    h0s[pw][hidx(c, wrU[ti])] = (_Float16)hv;
                }
            }
        } else {
            // ===== layer1: h1(s), s=t-1, from h0(s), h1(s-1) =====
            if (t > 0) {
                const int s = t - 1;
                const int prh0 = s & 1, prh1 = (s + 1) & 1, pwh1 = s & 1;
                const f16x8 b00 = *(const f16x8*)&h0s[prh0][rdB0];
                const f16x8 b01 = *(const f16x8*)&h0s[prh0][rdB1];
                const f16x8 b10 = *(const f16x8*)&h1s[prh1][rdB0];
                const f16x8 b11 = *(const f16x8*)&h1s[prh1][rdB1];
                f32x4 acc[2];
#pragma unroll
                for (int ti = 0; ti < 2; ++ti) {
                    f32x4 ci;
#pragma unroll
                    for (int r = 0; r < 4; ++r) ci[r] = bias[ti][r];
                    f32x4 aP = __builtin_amdgcn_mfma_f32_16x16x32_f16(aW[ti][0], b00, ci, 0, 0, 0);
                    aP = __builtin_amdgcn_mfma_f32_16x16x32_f16(aW[ti][1], b01, aP, 0, 0, 0);
                    f32x4 aQ = __builtin_amdgcn_mfma_f32_16x16x32_f16(aW[ti][2], b10, zf4, 0, 0, 0);
                    aQ = __builtin_amdgcn_mfma_f32_16x16x32_f16(aW[ti][3], b11, aQ, 0, 0, 0);
                    acc[ti] = aP + aQ;
                }
#pragma unroll
                for (int ti = 0; ti < 2; ++ti) {
                    const float hv = lstm_point(acc[ti][0], acc[ti][1],
                                                acc[ti][2], acc[ti][3], cst[ti]);
                    h1s[pwh1][hidx(c, wrU[ti])] = (_Float16)hv;
                }
            }
        }
        __syncthreads();
    }

    // ---- epilogue: h0(511), h1(511) both in parity 1 ----
    if (tid < 32) {
        const int which = tid >> 4, m = tid & 15;
        const _Float16* hb = which ? &h1s[1][0] : &h0s[1][0];
        float s = b_fc[0];
        for (int jj = 0; jj < 64; ++jj) s += (float)hb[hidx(m, jj)] * W_fc[jj];
        out[which * 1024 + b0 + m] = s;
    }
}

extern "C" void kernel_launch(void* const* d_in, const int* in_sizes, int n_in,
                              void* d_out, int out_size, void* d_ws, size_t ws_size,
                              hipStream_t stream) {
    (void)in_sizes; (void)n_in; (void)d_ws; (void)ws_size; (void)out_size;
    lstm2_kernel<<<64, 1024, 0, stream>>>(
        (const float*)d_in[0],
        (const float*)d_in[1], (const float*)d_in[2],
        (const float*)d_in[3], (const float*)d_in[4],
        (const float*)d_in[5], (const float*)d_in[6],
        (const float*)d_in[7], (const float*)d_in[8],
        (const float*)d_in[9], (const float*)d_in[10],
        (float*)d_out);
}